// Round 4
// baseline (3219.974 us; speedup 1.0000x reference)
//
#include <hip/hip_runtime.h>
#include <hip/hip_bf16.h>
#include <math.h>

// S=4096, D=512, H=8, hd=64, F=2048, E=8, top-2. I/O fp32.
// Attention path: split-bf16 (hi+lo, 3-MFMA) emulated-fp32 => routing matches
// fp32 reference. MoE expert GEMMs: plain bf16 MFMA (smooth error only).
#define SQ   4096
#define DM   512
#define NH   8
#define HDIM 64
#define FF   2048
#define NE   8

typedef unsigned short u16;
typedef unsigned int   u32;
typedef __attribute__((ext_vector_type(8))) __bf16 bf16x8;
typedef __attribute__((ext_vector_type(4))) float  f32x4;

__device__ __forceinline__ float bf2f(u16 v) {
    union { u32 i; float f; } c; c.i = ((u32)v) << 16; return c.f;
}
__device__ __forceinline__ u16 f2bf(float f) {  // RNE
    union { float f; u32 i; } c; c.f = f; u32 u = c.i;
    return (u16)((u + 0x7fffu + ((u >> 16) & 1u)) >> 16);
}

// ===========================================================================
// Split-bf16 GEMM (emulated fp32): C = (Ahi+Alo)[M,K] @ B[N,K]^T + bias
// acc += Ahi*Bhi + Ahi*Blo + Alo*Bhi   (3 MFMAs; residual ~2^-17)
// mode 0: write split pair Chi/Clo (bf16 each)
// mode 1: write fp32 Cf = acc + bias + resid
// ===========================================================================
#define BM 128
#define BN 128
#define BK 32

__global__ __launch_bounds__(256) void gemm_split(
    const u16* __restrict__ Ahi, const u16* __restrict__ Alo, int lda,
    const float* __restrict__ B, int ldb,
    int M, int N, int K,
    const float* __restrict__ bias,
    const float* __restrict__ resid, int ldres,
    u16* __restrict__ Chi, u16* __restrict__ Clo,
    float* __restrict__ Cf, int ldc, int mode)
{
    __shared__ __align__(16) u16 Ash[BM * BK];
    __shared__ __align__(16) u16 Asl[BM * BK];
    __shared__ __align__(16) u16 Bsh[BN * BK];
    __shared__ __align__(16) u16 Bsl[BN * BK];
    const int tid  = threadIdx.x;
    const int wave = tid >> 6;
    const int lane = tid & 63;
    const int quad = lane >> 4;
    const int l16  = lane & 15;
    const int bm = blockIdx.x * BM;
    const int bn = blockIdx.y * BN;
    const int wm = (wave & 1) * 64;
    const int wn = (wave >> 1) * 64;

    f32x4 acc[4][4];
#pragma unroll
    for (int i = 0; i < 4; i++)
#pragma unroll
        for (int j = 0; j < 4; j++)
#pragma unroll
            for (int r = 0; r < 4; r++) acc[i][j][r] = 0.0f;

    for (int k0 = 0; k0 < K; k0 += BK) {
#pragma unroll
        for (int i = 0; i < 2; i++) {
            int c = tid + i * 256;
            int row = c >> 2;
            int col = (c & 3) << 3;
            int gr = bm + row;
            uint4 vh = make_uint4(0u,0u,0u,0u), vl = make_uint4(0u,0u,0u,0u);
            if (gr < M) {
                vh = *(const uint4*)(Ahi + (size_t)gr * lda + k0 + col);
                vl = *(const uint4*)(Alo + (size_t)gr * lda + k0 + col);
            }
            *(uint4*)(Ash + row * BK + col) = vh;
            *(uint4*)(Asl + row * BK + col) = vl;
        }
#pragma unroll
        for (int i = 0; i < 4; i++) {
            int c = tid + i * 256;
            int row = c >> 3;
            int col = (c & 7) << 2;
            float4 v = make_float4(0.f,0.f,0.f,0.f);
            int gr = bn + row;
            if (gr < N) v = *(const float4*)(B + (size_t)gr * ldb + k0 + col);
            ushort4 h, l;
            h.x = f2bf(v.x); l.x = f2bf(v.x - bf2f(h.x));
            h.y = f2bf(v.y); l.y = f2bf(v.y - bf2f(h.y));
            h.z = f2bf(v.z); l.z = f2bf(v.z - bf2f(h.z));
            h.w = f2bf(v.w); l.w = f2bf(v.w - bf2f(h.w));
            *(ushort4*)(Bsh + row * BK + col) = h;
            *(ushort4*)(Bsl + row * BK + col) = l;
        }
        __syncthreads();
        bf16x8 ah[4], al[4], bh[4], bl[4];
#pragma unroll
        for (int i = 0; i < 4; i++) {
            ah[i] = *(const bf16x8*)(Ash + (wm + i * 16 + l16) * BK + quad * 8);
            al[i] = *(const bf16x8*)(Asl + (wm + i * 16 + l16) * BK + quad * 8);
        }
#pragma unroll
        for (int j = 0; j < 4; j++) {
            bh[j] = *(const bf16x8*)(Bsh + (wn + j * 16 + l16) * BK + quad * 8);
            bl[j] = *(const bf16x8*)(Bsl + (wn + j * 16 + l16) * BK + quad * 8);
        }
#pragma unroll
        for (int i = 0; i < 4; i++)
#pragma unroll
            for (int j = 0; j < 4; j++) {
                acc[i][j] = __builtin_amdgcn_mfma_f32_16x16x32_bf16(ah[i], bh[j], acc[i][j], 0,0,0);
                acc[i][j] = __builtin_amdgcn_mfma_f32_16x16x32_bf16(ah[i], bl[j], acc[i][j], 0,0,0);
                acc[i][j] = __builtin_amdgcn_mfma_f32_16x16x32_bf16(al[i], bh[j], acc[i][j], 0,0,0);
            }
        __syncthreads();
    }

#pragma unroll
    for (int i = 0; i < 4; i++)
#pragma unroll
        for (int j = 0; j < 4; j++)
#pragma unroll
            for (int r = 0; r < 4; r++) {
                int row = bm + wm + i * 16 + quad * 4 + r;
                int col = bn + wn + j * 16 + l16;
                if (row >= M || col >= N) continue;
                float v = acc[i][j][r] + (bias ? bias[col] : 0.0f);
                size_t idx = (size_t)row * ldc + col;
                if (mode == 0) {
                    u16 hb = f2bf(v);
                    Chi[idx] = hb;
                    Clo[idx] = f2bf(v - bf2f(hb));
                } else {
                    if (resid) v += resid[(size_t)row * ldres + col];
                    Cf[idx] = v;
                }
            }
}

// ===========================================================================
// Plain bf16 GEMM for MoE experts (A bf16, B fp32 staged->bf16).
// mode 0: Cb = bf16(acc+bias); mode 3: Cb = bf16(silu(Cb)*(acc+bias));
// mode 2: Cf = (init?0:Cf) + rowscale[r]*(acc+bias) + resid
// ===========================================================================
#define MODE_BF16 0
#define MODE_F32  2
#define MODE_SILU 3

__global__ __launch_bounds__(256) void gemm_bt(
    const u16* __restrict__ A, int lda,
    const float* __restrict__ B, int ldb,
    int M, int N, int K,
    const float* __restrict__ bias,
    const float* __restrict__ rowscale, int rs_stride,
    const float* __restrict__ resid, int ldres,
    u16* __restrict__ Cb, float* __restrict__ Cf, int ldc,
    int mode, int initacc)
{
    __shared__ __align__(16) u16 As[BM * BK];
    __shared__ __align__(16) u16 Bs[BN * BK];
    const int tid  = threadIdx.x;
    const int wave = tid >> 6;
    const int lane = tid & 63;
    const int quad = lane >> 4;
    const int l16  = lane & 15;
    const int bm = blockIdx.x * BM;
    const int bn = blockIdx.y * BN;
    const int wm = (wave & 1) * 64;
    const int wn = (wave >> 1) * 64;

    f32x4 acc[4][4];
#pragma unroll
    for (int i = 0; i < 4; i++)
#pragma unroll
        for (int j = 0; j < 4; j++)
#pragma unroll
            for (int r = 0; r < 4; r++) acc[i][j][r] = 0.0f;

    for (int k0 = 0; k0 < K; k0 += BK) {
#pragma unroll
        for (int i = 0; i < 2; i++) {
            int c = tid + i * 256;
            int row = c >> 2;
            int col = (c & 3) << 3;
            uint4 v = make_uint4(0u,0u,0u,0u);
            int gr = bm + row;
            if (gr < M) v = *(const uint4*)(A + (size_t)gr * lda + k0 + col);
            *(uint4*)(As + row * BK + col) = v;
        }
#pragma unroll
        for (int i = 0; i < 4; i++) {
            int c = tid + i * 256;
            int row = c >> 3;
            int col = (c & 7) << 2;
            float4 v = make_float4(0.f,0.f,0.f,0.f);
            int gr = bn + row;
            if (gr < N) v = *(const float4*)(B + (size_t)gr * ldb + k0 + col);
            ushort4 h;
            h.x = f2bf(v.x); h.y = f2bf(v.y); h.z = f2bf(v.z); h.w = f2bf(v.w);
            *(ushort4*)(Bs + row * BK + col) = h;
        }
        __syncthreads();
        bf16x8 af[4], bfr[4];
#pragma unroll
        for (int i = 0; i < 4; i++)
            af[i] = *(const bf16x8*)(As + (wm + i * 16 + l16) * BK + quad * 8);
#pragma unroll
        for (int j = 0; j < 4; j++)
            bfr[j] = *(const bf16x8*)(Bs + (wn + j * 16 + l16) * BK + quad * 8);
#pragma unroll
        for (int i = 0; i < 4; i++)
#pragma unroll
            for (int j = 0; j < 4; j++)
                acc[i][j] = __builtin_amdgcn_mfma_f32_16x16x32_bf16(
                    af[i], bfr[j], acc[i][j], 0, 0, 0);
        __syncthreads();
    }

#pragma unroll
    for (int i = 0; i < 4; i++)
#pragma unroll
        for (int j = 0; j < 4; j++)
#pragma unroll
            for (int r = 0; r < 4; r++) {
                int row = bm + wm + i * 16 + quad * 4 + r;
                int col = bn + wn + j * 16 + l16;
                if (row >= M || col >= N) continue;
                float a = acc[i][j][r];
                if (mode == MODE_BF16) {
                    Cb[(size_t)row * ldc + col] = f2bf(a + (bias ? bias[col] : 0.0f));
                } else if (mode == MODE_SILU) {
                    size_t idx = (size_t)row * ldc + col;
                    float g  = a + (bias ? bias[col] : 0.0f);
                    float a1 = bf2f(Cb[idx]);
                    float s  = a1 / (1.0f + __expf(-a1));
                    Cb[idx] = f2bf(s * g);
                } else {
                    size_t idx = (size_t)row * ldc + col;
                    float sc = rowscale ? rowscale[(size_t)row * rs_stride] : 1.0f;
                    float v = sc * (a + (bias ? bias[col] : 0.0f));
                    if (resid) v += resid[(size_t)row * ldres + col];
                    float prev = initacc ? 0.0f : Cf[idx];
                    Cf[idx] = prev + v;
                }
            }
}

// ===========================================================================
// Flash attention, split precision. grid (32 q-tiles, 8 heads), 256 thr.
// ===========================================================================
__global__ __launch_bounds__(256) void flash_attn(
    const u16* __restrict__ qh, const u16* __restrict__ ql,   // [4096,1536]
    const u16* __restrict__ vth, const u16* __restrict__ vtl, // [512,4096]
    u16* __restrict__ oh, u16* __restrict__ ol)               // [4096,512]
{
    __shared__ __align__(16) u16 Ksh[64*64], Ksl[64*64];
    __shared__ __align__(16) u16 Vsh[64*64], Vsl[64*64];
    __shared__ __align__(16) u16 Psh[4][32*64], Psl[4][32*64];
    const int tid  = threadIdx.x;
    const int wave = tid >> 6;
    const int lane = tid & 63;
    const int quad = lane >> 4;
    const int l16  = lane & 15;
    const int h    = blockIdx.y;
    const int qbase = blockIdx.x * 128 + wave * 32;

    bf16x8 aqh[2][2], aql[2][2];
#pragma unroll
    for (int mi = 0; mi < 2; mi++)
#pragma unroll
        for (int kk = 0; kk < 2; kk++) {
            size_t off = (size_t)(qbase + mi*16 + l16) * (3*DM) + h*HDIM + kk*32 + quad*8;
            aqh[mi][kk] = *(const bf16x8*)(qh + off);
            aql[mi][kk] = *(const bf16x8*)(ql + off);
        }

    float m_[2][4], l_[2][4];
    f32x4 o_[2][4];
#pragma unroll
    for (int mi = 0; mi < 2; mi++)
#pragma unroll
        for (int r = 0; r < 4; r++) { m_[mi][r] = -1e30f; l_[mi][r] = 0.0f; }
#pragma unroll
    for (int mi = 0; mi < 2; mi++)
#pragma unroll
        for (int nd = 0; nd < 4; nd++)
#pragma unroll
            for (int r = 0; r < 4; r++) o_[mi][nd][r] = 0.0f;

    for (int jt = 0; jt < SQ / 64; jt++) {
#pragma unroll
        for (int i = 0; i < 2; i++) {
            int c = tid + i * 256;
            int r = c >> 3;
            int co = (c & 7) << 3;
            size_t koff = (size_t)(jt*64 + r) * (3*DM) + DM + h*HDIM + co;
            size_t voff = (size_t)(h*HDIM + r) * SQ + jt*64 + co;
            *(uint4*)(Ksh + r*64 + co) = *(const uint4*)(qh + koff);
            *(uint4*)(Ksl + r*64 + co) = *(const uint4*)(ql + koff);
            *(uint4*)(Vsh + r*64 + co) = *(const uint4*)(vth + voff);
            *(uint4*)(Vsl + r*64 + co) = *(const uint4*)(vtl + voff);
        }
        __syncthreads();

        f32x4 s[2][4];
#pragma unroll
        for (int mi = 0; mi < 2; mi++)
#pragma unroll
            for (int jn = 0; jn < 4; jn++) {
                f32x4 z;
#pragma unroll
                for (int r = 0; r < 4; r++) z[r] = 0.0f;
#pragma unroll
                for (int kk = 0; kk < 2; kk++) {
                    bf16x8 kh = *(const bf16x8*)(Ksh + (jn*16 + l16)*64 + kk*32 + quad*8);
                    bf16x8 kl = *(const bf16x8*)(Ksl + (jn*16 + l16)*64 + kk*32 + quad*8);
                    z = __builtin_amdgcn_mfma_f32_16x16x32_bf16(aqh[mi][kk], kh, z, 0,0,0);
                    z = __builtin_amdgcn_mfma_f32_16x16x32_bf16(aqh[mi][kk], kl, z, 0,0,0);
                    z = __builtin_amdgcn_mfma_f32_16x16x32_bf16(aql[mi][kk], kh, z, 0,0,0);
                }
#pragma unroll
                for (int r = 0; r < 4; r++) z[r] *= 0.125f;
                s[mi][jn] = z;
            }

#pragma unroll
        for (int mi = 0; mi < 2; mi++) {
            float mx[4], al2[4], rs[4];
#pragma unroll
            for (int r = 0; r < 4; r++)
                mx[r] = fmaxf(fmaxf(s[mi][0][r], s[mi][1][r]),
                              fmaxf(s[mi][2][r], s[mi][3][r]));
#pragma unroll
            for (int r = 0; r < 4; r++) {
#pragma unroll
                for (int o2 = 1; o2 < 16; o2 <<= 1)
                    mx[r] = fmaxf(mx[r], __shfl_xor(mx[r], o2));
                float nm = fmaxf(m_[mi][r], mx[r]);
                al2[r] = __expf(m_[mi][r] - nm);
                m_[mi][r] = nm;
                rs[r] = 0.0f;
            }
#pragma unroll
            for (int jn = 0; jn < 4; jn++)
#pragma unroll
                for (int r = 0; r < 4; r++) {
                    float p = __expf(s[mi][jn][r] - m_[mi][r]);
                    s[mi][jn][r] = p;
                    rs[r] += p;
                }
#pragma unroll
            for (int r = 0; r < 4; r++) {
#pragma unroll
                for (int o2 = 1; o2 < 16; o2 <<= 1)
                    rs[r] += __shfl_xor(rs[r], o2);
                l_[mi][r] = l_[mi][r] * al2[r] + rs[r];
            }
#pragma unroll
            for (int nd = 0; nd < 4; nd++)
#pragma unroll
                for (int r = 0; r < 4; r++) o_[mi][nd][r] *= al2[r];
#pragma unroll
            for (int jn = 0; jn < 4; jn++)
#pragma unroll
                for (int r = 0; r < 4; r++) {
                    float p = s[mi][jn][r];
                    u16 ph = f2bf(p);
                    int pidx = (mi*16 + quad*4 + r)*64 + jn*16 + l16;
                    Psh[wave][pidx] = ph;
                    Psl[wave][pidx] = f2bf(p - bf2f(ph));
                }
        }
        __syncthreads();   // order P store vs reload

#pragma unroll
        for (int mi = 0; mi < 2; mi++) {
            bf16x8 ph[2], pl[2];
#pragma unroll
            for (int kk = 0; kk < 2; kk++) {
                ph[kk] = *(const bf16x8*)(Psh[wave] + (mi*16 + l16)*64 + kk*32 + quad*8);
                pl[kk] = *(const bf16x8*)(Psl[wave] + (mi*16 + l16)*64 + kk*32 + quad*8);
            }
#pragma unroll
            for (int nd = 0; nd < 4; nd++) {
#pragma unroll
                for (int kk = 0; kk < 2; kk++) {
                    bf16x8 vh = *(const bf16x8*)(Vsh + (nd*16 + l16)*64 + kk*32 + quad*8);
                    bf16x8 vl = *(const bf16x8*)(Vsl + (nd*16 + l16)*64 + kk*32 + quad*8);
                    o_[mi][nd] = __builtin_amdgcn_mfma_f32_16x16x32_bf16(ph[kk], vh, o_[mi][nd], 0,0,0);
                    o_[mi][nd] = __builtin_amdgcn_mfma_f32_16x16x32_bf16(ph[kk], vl, o_[mi][nd], 0,0,0);
                    o_[mi][nd] = __builtin_amdgcn_mfma_f32_16x16x32_bf16(pl[kk], vh, o_[mi][nd], 0,0,0);
                }
            }
        }
        __syncthreads();   // before next tile overwrites Ks/Vs
    }

#pragma unroll
    for (int mi = 0; mi < 2; mi++)
#pragma unroll
        for (int nd = 0; nd < 4; nd++)
#pragma unroll
            for (int r = 0; r < 4; r++) {
                int row = qbase + mi*16 + quad*4 + r;
                int col = h*HDIM + nd*16 + l16;
                float w = o_[mi][nd][r] / l_[mi][r];
                u16 hb = f2bf(w);
                oh[(size_t)row * DM + col] = hb;
                ol[(size_t)row * DM + col] = f2bf(w - bf2f(hb));
            }
}

// LN1: fp32 in -> split bf16 pair out. One block per row.
__global__ __launch_bounds__(256) void ln1_split(
    const float* __restrict__ x, const float* __restrict__ g,
    const float* __restrict__ b, u16* __restrict__ ohi, u16* __restrict__ olo)
{
    const int row = blockIdx.x;
    const int tid = threadIdx.x;
    float v0 = x[(size_t)row * DM + tid];
    float v1 = x[(size_t)row * DM + tid + 256];
    float s = v0 + v1, sq = v0*v0 + v1*v1;
#pragma unroll
    for (int o = 1; o < 64; o <<= 1) { s += __shfl_xor(s, o); sq += __shfl_xor(sq, o); }
    __shared__ float ss[4], ssq[4];
    if ((tid & 63) == 0) { ss[tid>>6] = s; ssq[tid>>6] = sq; }
    __syncthreads();
    s  = ss[0]+ss[1]+ss[2]+ss[3];
    sq = ssq[0]+ssq[1]+ssq[2]+ssq[3];
    float m = s * (1.0f/DM);
    float rstd = rsqrtf(sq*(1.0f/DM) - m*m + 1e-5f);
    float y0 = (v0-m)*rstd*g[tid]     + b[tid];
    float y1 = (v1-m)*rstd*g[tid+256] + b[tid+256];
    u16 h0 = f2bf(y0), h1 = f2bf(y1);
    ohi[(size_t)row*DM + tid]       = h0;  olo[(size_t)row*DM + tid]       = f2bf(y0 - bf2f(h0));
    ohi[(size_t)row*DM + tid + 256] = h1;  olo[(size_t)row*DM + tid + 256] = f2bf(y1 - bf2f(h1));
}

// LN2: fp32 in -> plain bf16 out (MoE expert A-operand)
__global__ __launch_bounds__(256) void ln_kernel(
    const float* __restrict__ x, const float* __restrict__ g,
    const float* __restrict__ b, u16* __restrict__ out)
{
    const int row = blockIdx.x;
    const int tid = threadIdx.x;
    float v0 = x[(size_t)row * DM + tid];
    float v1 = x[(size_t)row * DM + tid + 256];
    float s = v0 + v1, sq = v0*v0 + v1*v1;
#pragma unroll
    for (int o = 1; o < 64; o <<= 1) { s += __shfl_xor(s, o); sq += __shfl_xor(sq, o); }
    __shared__ float ss[4], ssq[4];
    if ((tid & 63) == 0) { ss[tid>>6] = s; ssq[tid>>6] = sq; }
    __syncthreads();
    s  = ss[0]+ss[1]+ss[2]+ss[3];
    sq = ssq[0]+ssq[1]+ssq[2]+ssq[3];
    float m = s * (1.0f/DM);
    float rstd = rsqrtf(sq*(1.0f/DM) - m*m + 1e-5f);
    out[(size_t)row*DM + tid]       = f2bf((v0-m)*rstd*g[tid]     + b[tid]);
    out[(size_t)row*DM + tid + 256] = f2bf((v1-m)*rstd*g[tid+256] + b[tid+256]);
}

// vt[(h*64+d)*4096 + t] = qkv[t*1536 + 1024 + h*64 + d], both split halves
__global__ __launch_bounds__(256) void transpose_v2(
    const u16* __restrict__ qh, const u16* __restrict__ ql,
    u16* __restrict__ vth, u16* __restrict__ vtl)
{
    int idx = blockIdx.x * 256 + threadIdx.x;
    int t   = idx & (SQ - 1);
    int hd_ = idx >> 12;
    size_t src = (size_t)t * (3*DM) + 2*DM + hd_;
    vth[idx] = qh[src];
    vtl[idx] = ql[src];
}

// Gate with its own fp32 LN2 from x1 (routing stays fp32-faithful).
// One wave per token; top-2 of softmax over E=8, NOT renormalized.
__global__ __launch_bounds__(256) void gate_ln_kernel(
    const float* __restrict__ x1, const float* __restrict__ g,
    const float* __restrict__ b, const float* __restrict__ gw,
    const float* __restrict__ gb, float* __restrict__ comb)
{
    const int token = blockIdx.x * 4 + (threadIdx.x >> 6);
    const int lane  = threadIdx.x & 63;
    const float* xr = x1 + (size_t)token * DM;
    float v[8];
#pragma unroll
    for (int i = 0; i < 8; i++) v[i] = xr[lane*8 + i];
    float s = 0.f, sq = 0.f;
#pragma unroll
    for (int i = 0; i < 8; i++) { s += v[i]; sq += v[i]*v[i]; }
#pragma unroll
    for (int o = 1; o < 64; o <<= 1) { s += __shfl_xor(s, o); sq += __shfl_xor(sq, o); }
    float m = s * (1.0f/DM);
    float rstd = rsqrtf(sq*(1.0f/DM) - m*m + 1e-5f);
    float xn[8];
#pragma unroll
    for (int i = 0; i < 8; i++)
        xn[i] = (v[i]-m)*rstd*g[lane*8+i] + b[lane*8+i];
    float logit[8];
#pragma unroll
    for (int e = 0; e < 8; e++) {
        float t = 0.f;
#pragma unroll
        for (int i = 0; i < 8; i++) t += xn[i] * gw[e*DM + lane*8 + i];
#pragma unroll
        for (int o = 1; o < 64; o <<= 1) t += __shfl_xor(t, o);
        logit[e] = t + gb[e];
    }
    if (lane == 0) {
        float mx = -1e30f;
        for (int e = 0; e < 8; e++) mx = fmaxf(mx, logit[e]);
        float den = 0.f, p[8];
        for (int e = 0; e < 8; e++) { p[e] = __expf(logit[e] - mx); den += p[e]; }
        for (int e = 0; e < 8; e++) p[e] /= den;
        int i1 = 0;
        for (int e = 1; e < 8; e++) if (p[e] > p[i1]) i1 = e;
        int i2 = -1;
        for (int e = 0; e < 8; e++) { if (e == i1) continue; if (i2 < 0 || p[e] > p[i2]) i2 = e; }
        for (int e = 0; e < 8; e++) comb[token*8 + e] = (e == i1 || e == i2) ? p[e] : 0.0f;
    }
}

__global__ __launch_bounds__(256) void sentinel_kernel(float* out, float v, int n)
{
    int i = blockIdx.x * 256 + threadIdx.x;
    if (i < n) out[i] = v;
}
__global__ __launch_bounds__(256) void scrub_kernel(float* out, int n)
{
    int i = blockIdx.x * 256 + threadIdx.x;
    if (i < n) { float v = out[i]; if (!isfinite(v)) out[i] = 777.0f; }
}

// ===========================================================================
extern "C" void kernel_launch(void* const* d_in, const int* in_sizes, int n_in,
                              void* d_out, int out_size, void* d_ws, size_t ws_size,
                              hipStream_t stream)
{
    const float* src        = (const float*)d_in[0];
    const float* in_proj_w  = (const float*)d_in[1];
    const float* in_proj_b  = (const float*)d_in[2];
    const float* out_proj_w = (const float*)d_in[3];
    const float* out_proj_b = (const float*)d_in[4];
    const float* ln1_g      = (const float*)d_in[5];
    const float* ln1_b      = (const float*)d_in[6];
    const float* ln2_g      = (const float*)d_in[7];
    const float* ln2_b      = (const float*)d_in[8];
    const float* gate_w     = (const float*)d_in[9];
    const float* gate_b     = (const float*)d_in[10];
    const float* w1         = (const float*)d_in[11];
    const float* b1         = (const float*)d_in[12];
    const float* w2         = (const float*)d_in[13];
    const float* b2         = (const float*)d_in[14];
    const float* wo         = (const float*)d_in[15];
    const float* bo         = (const float*)d_in[16];
    float* out = (float*)d_out;

    const size_t MB = (size_t)1 << 20;
    const size_t NEED = 48 * MB + 128 * 1024;
    if (ws_size < NEED) {   // diagnostic: ws too small -> absmax ~333
        sentinel_kernel<<<(SQ*DM)/256, 256, 0, stream>>>(out, 333.0f, SQ*DM);
        return;
    }

    // workspace (peak 48.13 MiB, phase reuse; every byte written before read)
    char* ws = (char*)d_ws;
    float* comb = (float*)ws;                       // 128 KiB
    char*  base = ws + 128 * 1024;
    u16* xln1h = (u16*)(base);                      // [0,4M)   phase A
    u16* xln1l = (u16*)(base + 4*MB);               // [4M,8M)  phase A
    u16* attnh = (u16*)(base);                      // [0,4M)   phase B (xln1 dead)
    u16* attnl = (u16*)(base + 4*MB);               // [4M,8M)  phase B
    u16* qkvh  = (u16*)(base + 8*MB);               // [8M,20M)
    u16* qkvl  = (u16*)(base + 20*MB);              // [20M,32M)
    u16* vth   = (u16*)(base + 32*MB);              // [32M,36M)
    u16* vtl   = (u16*)(base + 36*MB);              // [36M,40M)
    float* x1  = (float*)(base + 40*MB);            // [40M,48M) fp32
    u16* xln2  = (u16*)(base + 32*MB);              // [32M,36M) phase C (vt dead)
    u16* a1    = (u16*)(base + 8*MB);               // [8M,24M)  phase D (qkv dead)

    // ---- attention path (emulated fp32) ----
    ln1_split<<<SQ, 256, 0, stream>>>(src, ln1_g, ln1_b, xln1h, xln1l);
    gemm_split<<<dim3(32, 12), 256, 0, stream>>>(           // qkv (split out)
        xln1h, xln1l, DM, in_proj_w, DM, SQ, 3*DM, DM,
        in_proj_b, nullptr, 0, qkvh, qkvl, nullptr, 3*DM, 0);
    transpose_v2<<<(NH*HDIM*SQ)/256, 256, 0, stream>>>(qkvh, qkvl, vth, vtl);
    flash_attn<<<dim3(SQ/128, NH), 256, 0, stream>>>(qkvh, qkvl, vth, vtl, attnh, attnl);

    // x1 = src + attn @ out_proj_w^T + b  (fp32)
    gemm_split<<<dim3(32, 4), 256, 0, stream>>>(
        attnh, attnl, DM, out_proj_w, DM, SQ, DM, DM,
        out_proj_b, src, DM, nullptr, nullptr, x1, DM, 1);

    // ---- MoE ----
    ln_kernel<<<SQ, 256, 0, stream>>>(x1, ln2_g, ln2_b, xln2);
    gate_ln_kernel<<<SQ/4, 256, 0, stream>>>(x1, ln2_g, ln2_b, gate_w, gate_b, comb);

    for (int e = 0; e < NE; e++) {
        gemm_bt<<<dim3(32, 16), 256, 0, stream>>>(          // a1 = x@w1^T+b1
            xln2, DM, w1 + (size_t)e*FF*DM, DM, SQ, FF, DM,
            b1 + e*FF, nullptr, 0, nullptr, 0, a1, nullptr, FF, MODE_BF16, 0);
        gemm_bt<<<dim3(32, 16), 256, 0, stream>>>(          // h=silu(a1)*(x@w2^T+b2)
            xln2, DM, w2 + (size_t)e*FF*DM, DM, SQ, FF, DM,
            b2 + e*FF, nullptr, 0, nullptr, 0, a1, nullptr, FF, MODE_SILU, 0);
        gemm_bt<<<dim3(32, 4), 256, 0, stream>>>(           // out (+)= comb*(h@wo^T+bo) [+x1 @ e0]
            a1, FF, wo + (size_t)e*DM*FF, FF, SQ, DM, FF,
            bo + e*DM, comb + e, NE, (e == 0) ? x1 : nullptr, DM,
            nullptr, out, DM, MODE_F32, (e == 0) ? 1 : 0);
    }

    scrub_kernel<<<(SQ*DM)/256, 256, 0, stream>>>(out, SQ*DM);
}

// Round 5
// 1879.426 us; speedup vs baseline: 1.7133x; 1.7133x over previous
//
#include <hip/hip_runtime.h>
#include <hip/hip_bf16.h>
#include <math.h>

// S=4096, D=512, H=8, hd=64, F=2048, E=8, top-2. I/O fp32.
// Attention path: split-bf16 (hi+lo, 3-MFMA) emulated fp32 => fp32-faithful
// routing. MoE: sparse top-2 (compacted per-expert token lists), plain bf16.
#define SQ   4096
#define DM   512
#define NH   8
#define HDIM 64
#define FF   2048
#define NE   8

typedef unsigned short u16;
typedef unsigned int   u32;
typedef __attribute__((ext_vector_type(8))) __bf16 bf16x8;
typedef __attribute__((ext_vector_type(4))) float  f32x4;

__device__ __forceinline__ float bf2f(u16 v) {
    union { u32 i; float f; } c; c.i = ((u32)v) << 16; return c.f;
}
__device__ __forceinline__ u16 f2bf(float f) {  // RNE
    union { float f; u32 i; } c; c.f = f; u32 u = c.i;
    return (u16)((u + 0x7fffu + ((u >> 16) & 1u)) >> 16);
}

#define BM 128
#define BN 128
#define BK 32
#define BKP 40   // padded LDS row stride (40 u16 = 20 dwords -> 2-way, free)

// ===========================================================================
// Split-bf16 GEMM: C = (Ahi+Alo)@(Bhi+Blo)^T + bias. 3 MFMAs (hh+hl+lh).
// mode 0: split bf16 pair out. mode 1: fp32 out (+resid).
// ===========================================================================
__global__ __launch_bounds__(256) void gemm_split(
    const u16* __restrict__ Ahi, const u16* __restrict__ Alo, int lda,
    const u16* __restrict__ Bhi, const u16* __restrict__ Blo, int ldb,
    int M, int N, int K,
    const float* __restrict__ bias,
    const float* __restrict__ resid, int ldres,
    u16* __restrict__ Chi, u16* __restrict__ Clo,
    float* __restrict__ Cf, int ldc, int mode)
{
    __shared__ __align__(16) u16 Ash[BM * BKP], Asl[BM * BKP];
    __shared__ __align__(16) u16 Bsh[BN * BKP], Bsl[BN * BKP];
    const int tid  = threadIdx.x;
    const int wave = tid >> 6;
    const int lane = tid & 63;
    const int quad = lane >> 4;
    const int l16  = lane & 15;
    const int bm = blockIdx.x * BM;
    const int bn = blockIdx.y * BN;
    const int wm = (wave & 1) * 64;
    const int wn = (wave >> 1) * 64;

    f32x4 acc[4][4];
#pragma unroll
    for (int i = 0; i < 4; i++)
#pragma unroll
        for (int j = 0; j < 4; j++)
#pragma unroll
            for (int r = 0; r < 4; r++) acc[i][j][r] = 0.0f;

    for (int k0 = 0; k0 < K; k0 += BK) {
#pragma unroll
        for (int i = 0; i < 2; i++) {
            int c = tid + i * 256;
            int row = c >> 2;
            int col = (c & 3) << 3;
            int ga = bm + row, gb2 = bn + row;
            uint4 vah = make_uint4(0u,0u,0u,0u), val = vah, vbh = vah, vbl = vah;
            if (ga < M) {
                vah = *(const uint4*)(Ahi + (size_t)ga * lda + k0 + col);
                val = *(const uint4*)(Alo + (size_t)ga * lda + k0 + col);
            }
            if (gb2 < N) {
                vbh = *(const uint4*)(Bhi + (size_t)gb2 * ldb + k0 + col);
                vbl = *(const uint4*)(Blo + (size_t)gb2 * ldb + k0 + col);
            }
            *(uint4*)(Ash + row * BKP + col) = vah;
            *(uint4*)(Asl + row * BKP + col) = val;
            *(uint4*)(Bsh + row * BKP + col) = vbh;
            *(uint4*)(Bsl + row * BKP + col) = vbl;
        }
        __syncthreads();
        bf16x8 ah[4], al[4], bh[4], bl[4];
#pragma unroll
        for (int i = 0; i < 4; i++) {
            ah[i] = *(const bf16x8*)(Ash + (wm + i * 16 + l16) * BKP + quad * 8);
            al[i] = *(const bf16x8*)(Asl + (wm + i * 16 + l16) * BKP + quad * 8);
        }
#pragma unroll
        for (int j = 0; j < 4; j++) {
            bh[j] = *(const bf16x8*)(Bsh + (wn + j * 16 + l16) * BKP + quad * 8);
            bl[j] = *(const bf16x8*)(Bsl + (wn + j * 16 + l16) * BKP + quad * 8);
        }
#pragma unroll
        for (int i = 0; i < 4; i++)
#pragma unroll
            for (int j = 0; j < 4; j++) {
                acc[i][j] = __builtin_amdgcn_mfma_f32_16x16x32_bf16(ah[i], bh[j], acc[i][j], 0,0,0);
                acc[i][j] = __builtin_amdgcn_mfma_f32_16x16x32_bf16(ah[i], bl[j], acc[i][j], 0,0,0);
                acc[i][j] = __builtin_amdgcn_mfma_f32_16x16x32_bf16(al[i], bh[j], acc[i][j], 0,0,0);
            }
        __syncthreads();
    }

#pragma unroll
    for (int i = 0; i < 4; i++)
#pragma unroll
        for (int j = 0; j < 4; j++)
#pragma unroll
            for (int r = 0; r < 4; r++) {
                int row = bm + wm + i * 16 + quad * 4 + r;
                int col = bn + wn + j * 16 + l16;
                if (row >= M || col >= N) continue;
                float v = acc[i][j][r] + (bias ? bias[col] : 0.0f);
                size_t idx = (size_t)row * ldc + col;
                if (mode == 0) {
                    u16 hb = f2bf(v);
                    Chi[idx] = hb;
                    Clo[idx] = f2bf(v - bf2f(hb));
                } else {
                    if (resid) v += resid[(size_t)row * ldres + col];
                    Cf[idx] = v;
                }
            }
}

// ===========================================================================
// Fused MoE w1/w2 GEMM (sparse): h = silu(x@w1^T+b1) * (x@w2^T+b2)
// A rows gathered via ridxA; M dynamic (*Mptr). B1/B2 pre-converted bf16.
// ===========================================================================
__global__ __launch_bounds__(256) void gemm_moe12(
    const u16* __restrict__ A, int lda, const int* __restrict__ ridxA,
    const u16* __restrict__ B1, const u16* __restrict__ B2, int ldb,
    const int* __restrict__ Mptr, int N, int K,
    const float* __restrict__ bias1, const float* __restrict__ bias2,
    u16* __restrict__ Cb, int ldc)
{
    const int M = *Mptr;
    const int bm = blockIdx.x * BM;
    if (bm >= M) return;
    __shared__ __align__(16) u16 As[BM * BKP], Bs1[BN * BKP], Bs2[BN * BKP];
    const int tid  = threadIdx.x;
    const int wave = tid >> 6;
    const int lane = tid & 63;
    const int quad = lane >> 4;
    const int l16  = lane & 15;
    const int bn = blockIdx.y * BN;
    const int wm = (wave & 1) * 64;
    const int wn = (wave >> 1) * 64;

    f32x4 acc1[4][4], acc2[4][4];
#pragma unroll
    for (int i = 0; i < 4; i++)
#pragma unroll
        for (int j = 0; j < 4; j++)
#pragma unroll
            for (int r = 0; r < 4; r++) { acc1[i][j][r] = 0.0f; acc2[i][j][r] = 0.0f; }

    for (int k0 = 0; k0 < K; k0 += BK) {
#pragma unroll
        for (int i = 0; i < 2; i++) {
            int c = tid + i * 256;
            int row = c >> 2;
            int col = (c & 3) << 3;
            int ga = bm + row, gb2 = bn + row;
            uint4 va = make_uint4(0u,0u,0u,0u), vb1 = va, vb2 = va;
            if (ga < M) {
                int ar = ridxA ? ridxA[ga] : ga;
                va = *(const uint4*)(A + (size_t)ar * lda + k0 + col);
            }
            if (gb2 < N) {
                vb1 = *(const uint4*)(B1 + (size_t)gb2 * ldb + k0 + col);
                vb2 = *(const uint4*)(B2 + (size_t)gb2 * ldb + k0 + col);
            }
            *(uint4*)(As  + row * BKP + col) = va;
            *(uint4*)(Bs1 + row * BKP + col) = vb1;
            *(uint4*)(Bs2 + row * BKP + col) = vb2;
        }
        __syncthreads();
        bf16x8 af[4], b1f[4], b2f[4];
#pragma unroll
        for (int i = 0; i < 4; i++)
            af[i] = *(const bf16x8*)(As + (wm + i * 16 + l16) * BKP + quad * 8);
#pragma unroll
        for (int j = 0; j < 4; j++) {
            b1f[j] = *(const bf16x8*)(Bs1 + (wn + j * 16 + l16) * BKP + quad * 8);
            b2f[j] = *(const bf16x8*)(Bs2 + (wn + j * 16 + l16) * BKP + quad * 8);
        }
#pragma unroll
        for (int i = 0; i < 4; i++)
#pragma unroll
            for (int j = 0; j < 4; j++) {
                acc1[i][j] = __builtin_amdgcn_mfma_f32_16x16x32_bf16(af[i], b1f[j], acc1[i][j], 0,0,0);
                acc2[i][j] = __builtin_amdgcn_mfma_f32_16x16x32_bf16(af[i], b2f[j], acc2[i][j], 0,0,0);
            }
        __syncthreads();
    }

#pragma unroll
    for (int i = 0; i < 4; i++)
#pragma unroll
        for (int j = 0; j < 4; j++)
#pragma unroll
            for (int r = 0; r < 4; r++) {
                int row = bm + wm + i * 16 + quad * 4 + r;
                int col = bn + wn + j * 16 + l16;
                if (row >= M || col >= N) continue;
                float g1 = acc1[i][j][r] + bias1[col];
                float g2 = acc2[i][j][r] + bias2[col];
                float s  = g1 / (1.0f + __expf(-g1));
                Cb[(size_t)row * ldc + col] = f2bf(s * g2);
            }
}

// ===========================================================================
// MoE down-proj GEMM (sparse): out[ridxC[r]] += cwl[r]*(h@wo^T + bo)
// ===========================================================================
__global__ __launch_bounds__(256) void gemm_moe_y(
    const u16* __restrict__ A, int lda,
    const u16* __restrict__ B, int ldb,
    const int* __restrict__ Mptr, int N, int K,
    const float* __restrict__ bias,
    const float* __restrict__ cwl, const int* __restrict__ ridxC,
    float* __restrict__ Cf, int ldc)
{
    const int M = *Mptr;
    const int bm = blockIdx.x * BM;
    if (bm >= M) return;
    __shared__ __align__(16) u16 As[BM * BKP], Bs[BN * BKP];
    const int tid  = threadIdx.x;
    const int wave = tid >> 6;
    const int lane = tid & 63;
    const int quad = lane >> 4;
    const int l16  = lane & 15;
    const int bn = blockIdx.y * BN;
    const int wm = (wave & 1) * 64;
    const int wn = (wave >> 1) * 64;

    f32x4 acc[4][4];
#pragma unroll
    for (int i = 0; i < 4; i++)
#pragma unroll
        for (int j = 0; j < 4; j++)
#pragma unroll
            for (int r = 0; r < 4; r++) acc[i][j][r] = 0.0f;

    for (int k0 = 0; k0 < K; k0 += BK) {
#pragma unroll
        for (int i = 0; i < 2; i++) {
            int c = tid + i * 256;
            int row = c >> 2;
            int col = (c & 3) << 3;
            int ga = bm + row, gb2 = bn + row;
            uint4 va = make_uint4(0u,0u,0u,0u), vb = va;
            if (ga < M) va = *(const uint4*)(A + (size_t)ga * lda + k0 + col);
            if (gb2 < N) vb = *(const uint4*)(B + (size_t)gb2 * ldb + k0 + col);
            *(uint4*)(As + row * BKP + col) = va;
            *(uint4*)(Bs + row * BKP + col) = vb;
        }
        __syncthreads();
        bf16x8 af[4], bf[4];
#pragma unroll
        for (int i = 0; i < 4; i++)
            af[i] = *(const bf16x8*)(As + (wm + i * 16 + l16) * BKP + quad * 8);
#pragma unroll
        for (int j = 0; j < 4; j++)
            bf[j] = *(const bf16x8*)(Bs + (wn + j * 16 + l16) * BKP + quad * 8);
#pragma unroll
        for (int i = 0; i < 4; i++)
#pragma unroll
            for (int j = 0; j < 4; j++)
                acc[i][j] = __builtin_amdgcn_mfma_f32_16x16x32_bf16(af[i], bf[j], acc[i][j], 0,0,0);
        __syncthreads();
    }

#pragma unroll
    for (int i = 0; i < 4; i++)
#pragma unroll
        for (int j = 0; j < 4; j++)
#pragma unroll
            for (int r = 0; r < 4; r++) {
                int row = bm + wm + i * 16 + quad * 4 + r;
                int col = bn + wn + j * 16 + l16;
                if (row >= M || col >= N) continue;
                int cr = ridxC[row];
                size_t idx = (size_t)cr * ldc + col;
                Cf[idx] += cwl[row] * (acc[i][j][r] + bias[col]);
            }
}

// ===========================================================================
// Flash attention, split precision. 64-row Q tiles, grid (64, 8), 256 thr,
// 4 waves x 16 rows. LDS rows padded to 72 u16 (kills 16-way conflicts).
// ===========================================================================
#define KP 72
__global__ __launch_bounds__(256) void flash_attn(
    const u16* __restrict__ qh, const u16* __restrict__ ql,   // [4096,1536]
    const u16* __restrict__ vth, const u16* __restrict__ vtl, // [512,4096]
    u16* __restrict__ oh, u16* __restrict__ ol)               // [4096,512]
{
    __shared__ __align__(16) u16 Ksh[64*KP], Ksl[64*KP], Vsh[64*KP], Vsl[64*KP];
    __shared__ __align__(16) u16 Psh[4][16*KP], Psl[4][16*KP];
    const int tid  = threadIdx.x;
    const int wave = tid >> 6;
    const int lane = tid & 63;
    const int quad = lane >> 4;
    const int l16  = lane & 15;
    const int h    = blockIdx.y;
    const int qbase = blockIdx.x * 64 + wave * 16;

    bf16x8 aqh[2], aql[2];
#pragma unroll
    for (int kk = 0; kk < 2; kk++) {
        size_t off = (size_t)(qbase + l16) * (3*DM) + h*HDIM + kk*32 + quad*8;
        aqh[kk] = *(const bf16x8*)(qh + off);
        aql[kk] = *(const bf16x8*)(ql + off);
    }

    float m_[4], l_[4];
    f32x4 o_[4];
#pragma unroll
    for (int r = 0; r < 4; r++) { m_[r] = -1e30f; l_[r] = 0.0f; }
#pragma unroll
    for (int nd = 0; nd < 4; nd++)
#pragma unroll
        for (int r = 0; r < 4; r++) o_[nd][r] = 0.0f;

    for (int jt = 0; jt < SQ / 64; jt++) {
#pragma unroll
        for (int i = 0; i < 2; i++) {
            int c = tid + i * 256;
            int r = c >> 3;
            int co = (c & 7) << 3;
            size_t koff = (size_t)(jt*64 + r) * (3*DM) + DM + h*HDIM + co;
            size_t voff = (size_t)(h*HDIM + r) * SQ + jt*64 + co;
            *(uint4*)(Ksh + r*KP + co) = *(const uint4*)(qh + koff);
            *(uint4*)(Ksl + r*KP + co) = *(const uint4*)(ql + koff);
            *(uint4*)(Vsh + r*KP + co) = *(const uint4*)(vth + voff);
            *(uint4*)(Vsl + r*KP + co) = *(const uint4*)(vtl + voff);
        }
        __syncthreads();

        f32x4 s[4];
#pragma unroll
        for (int jn = 0; jn < 4; jn++) {
            f32x4 z;
#pragma unroll
            for (int r = 0; r < 4; r++) z[r] = 0.0f;
#pragma unroll
            for (int kk = 0; kk < 2; kk++) {
                bf16x8 kh = *(const bf16x8*)(Ksh + (jn*16 + l16)*KP + kk*32 + quad*8);
                bf16x8 kl = *(const bf16x8*)(Ksl + (jn*16 + l16)*KP + kk*32 + quad*8);
                z = __builtin_amdgcn_mfma_f32_16x16x32_bf16(aqh[kk], kh, z, 0,0,0);
                z = __builtin_amdgcn_mfma_f32_16x16x32_bf16(aqh[kk], kl, z, 0,0,0);
                z = __builtin_amdgcn_mfma_f32_16x16x32_bf16(aql[kk], kh, z, 0,0,0);
            }
#pragma unroll
            for (int r = 0; r < 4; r++) z[r] *= 0.125f;
            s[jn] = z;
        }

        float mx[4], al2[4], rs[4];
#pragma unroll
        for (int r = 0; r < 4; r++)
            mx[r] = fmaxf(fmaxf(s[0][r], s[1][r]), fmaxf(s[2][r], s[3][r]));
#pragma unroll
        for (int r = 0; r < 4; r++) {
#pragma unroll
            for (int o2 = 1; o2 < 16; o2 <<= 1)
                mx[r] = fmaxf(mx[r], __shfl_xor(mx[r], o2));
            float nm = fmaxf(m_[r], mx[r]);
            al2[r] = __expf(m_[r] - nm);
            m_[r] = nm;
            rs[r] = 0.0f;
        }
#pragma unroll
        for (int jn = 0; jn < 4; jn++)
#pragma unroll
            for (int r = 0; r < 4; r++) {
                float p = __expf(s[jn][r] - m_[r]);
                s[jn][r] = p;
                rs[r] += p;
            }
#pragma unroll
        for (int r = 0; r < 4; r++) {
#pragma unroll
            for (int o2 = 1; o2 < 16; o2 <<= 1)
                rs[r] += __shfl_xor(rs[r], o2);
            l_[r] = l_[r] * al2[r] + rs[r];
        }
#pragma unroll
        for (int nd = 0; nd < 4; nd++)
#pragma unroll
            for (int r = 0; r < 4; r++) o_[nd][r] *= al2[r];
#pragma unroll
        for (int jn = 0; jn < 4; jn++)
#pragma unroll
            for (int r = 0; r < 4; r++) {
                float p = s[jn][r];
                u16 ph = f2bf(p);
                int pidx = (quad*4 + r)*KP + jn*16 + l16;
                Psh[wave][pidx] = ph;
                Psl[wave][pidx] = f2bf(p - bf2f(ph));
            }
        __syncthreads();   // order P store vs reload

        bf16x8 ph[2], pl[2];
#pragma unroll
        for (int kk = 0; kk < 2; kk++) {
            ph[kk] = *(const bf16x8*)(Psh[wave] + l16*KP + kk*32 + quad*8);
            pl[kk] = *(const bf16x8*)(Psl[wave] + l16*KP + kk*32 + quad*8);
        }
#pragma unroll
        for (int nd = 0; nd < 4; nd++) {
#pragma unroll
            for (int kk = 0; kk < 2; kk++) {
                bf16x8 vh = *(const bf16x8*)(Vsh + (nd*16 + l16)*KP + kk*32 + quad*8);
                bf16x8 vl = *(const bf16x8*)(Vsl + (nd*16 + l16)*KP + kk*32 + quad*8);
                o_[nd] = __builtin_amdgcn_mfma_f32_16x16x32_bf16(ph[kk], vh, o_[nd], 0,0,0);
                o_[nd] = __builtin_amdgcn_mfma_f32_16x16x32_bf16(ph[kk], vl, o_[nd], 0,0,0);
                o_[nd] = __builtin_amdgcn_mfma_f32_16x16x32_bf16(pl[kk], vh, o_[nd], 0,0,0);
            }
        }
        __syncthreads();   // before next tile overwrites Ks/Vs
    }

#pragma unroll
    for (int nd = 0; nd < 4; nd++)
#pragma unroll
        for (int r = 0; r < 4; r++) {
            int row = qbase + quad*4 + r;
            int col = h*HDIM + nd*16 + l16;
            float w = o_[nd][r] / l_[r];
            u16 hb = f2bf(w);
            oh[(size_t)row * DM + col] = hb;
            ol[(size_t)row * DM + col] = f2bf(w - bf2f(hb));
        }
}

// LN1: fp32 in -> split bf16 pair out.
__global__ __launch_bounds__(256) void ln1_split(
    const float* __restrict__ x, const float* __restrict__ g,
    const float* __restrict__ b, u16* __restrict__ ohi, u16* __restrict__ olo)
{
    const int row = blockIdx.x;
    const int tid = threadIdx.x;
    float v0 = x[(size_t)row * DM + tid];
    float v1 = x[(size_t)row * DM + tid + 256];
    float s = v0 + v1, sq = v0*v0 + v1*v1;
#pragma unroll
    for (int o = 1; o < 64; o <<= 1) { s += __shfl_xor(s, o); sq += __shfl_xor(sq, o); }
    __shared__ float ss[4], ssq[4];
    if ((tid & 63) == 0) { ss[tid>>6] = s; ssq[tid>>6] = sq; }
    __syncthreads();
    s  = ss[0]+ss[1]+ss[2]+ss[3];
    sq = ssq[0]+ssq[1]+ssq[2]+ssq[3];
    float m = s * (1.0f/DM);
    float rstd = rsqrtf(sq*(1.0f/DM) - m*m + 1e-5f);
    float y0 = (v0-m)*rstd*g[tid]     + b[tid];
    float y1 = (v1-m)*rstd*g[tid+256] + b[tid+256];
    u16 h0 = f2bf(y0), h1 = f2bf(y1);
    ohi[(size_t)row*DM + tid]       = h0;  olo[(size_t)row*DM + tid]       = f2bf(y0 - bf2f(h0));
    ohi[(size_t)row*DM + tid + 256] = h1;  olo[(size_t)row*DM + tid + 256] = f2bf(y1 - bf2f(h1));
}

// LN2: fp32 in -> plain bf16 out
__global__ __launch_bounds__(256) void ln_kernel(
    const float* __restrict__ x, const float* __restrict__ g,
    const float* __restrict__ b, u16* __restrict__ out)
{
    const int row = blockIdx.x;
    const int tid = threadIdx.x;
    float v0 = x[(size_t)row * DM + tid];
    float v1 = x[(size_t)row * DM + tid + 256];
    float s = v0 + v1, sq = v0*v0 + v1*v1;
#pragma unroll
    for (int o = 1; o < 64; o <<= 1) { s += __shfl_xor(s, o); sq += __shfl_xor(sq, o); }
    __shared__ float ss[4], ssq[4];
    if ((tid & 63) == 0) { ss[tid>>6] = s; ssq[tid>>6] = sq; }
    __syncthreads();
    s  = ss[0]+ss[1]+ss[2]+ss[3];
    sq = ssq[0]+ssq[1]+ssq[2]+ssq[3];
    float m = s * (1.0f/DM);
    float rstd = rsqrtf(sq*(1.0f/DM) - m*m + 1e-5f);
    out[(size_t)row*DM + tid]       = f2bf((v0-m)*rstd*g[tid]     + b[tid]);
    out[(size_t)row*DM + tid + 256] = f2bf((v1-m)*rstd*g[tid+256] + b[tid+256]);
}

// vt[(h*64+d)*4096 + t] = qkv[t*1536 + 1024 + h*64 + d], both halves
__global__ __launch_bounds__(256) void transpose_v2(
    const u16* __restrict__ qh, const u16* __restrict__ ql,
    u16* __restrict__ vth, u16* __restrict__ vtl)
{
    int idx = blockIdx.x * 256 + threadIdx.x;
    int t   = idx & (SQ - 1);
    int hd_ = idx >> 12;
    size_t src = (size_t)t * (3*DM) + 2*DM + hd_;
    vth[idx] = qh[src];
    vtl[idx] = ql[src];
}

// Gate (own fp32 LN2) + top-2 compaction into per-expert lists.
__global__ __launch_bounds__(256) void gate_route(
    const float* __restrict__ x1, const float* __restrict__ g,
    const float* __restrict__ b, const float* __restrict__ gw,
    const float* __restrict__ gb,
    int* __restrict__ cnt, int* __restrict__ idxl, float* __restrict__ cw)
{
    const int token = blockIdx.x * 4 + (threadIdx.x >> 6);
    const int lane  = threadIdx.x & 63;
    const float* xr = x1 + (size_t)token * DM;
    float v[8];
#pragma unroll
    for (int i = 0; i < 8; i++) v[i] = xr[lane*8 + i];
    float s = 0.f, sq = 0.f;
#pragma unroll
    for (int i = 0; i < 8; i++) { s += v[i]; sq += v[i]*v[i]; }
#pragma unroll
    for (int o = 1; o < 64; o <<= 1) { s += __shfl_xor(s, o); sq += __shfl_xor(sq, o); }
    float m = s * (1.0f/DM);
    float rstd = rsqrtf(sq*(1.0f/DM) - m*m + 1e-5f);
    float xn[8];
#pragma unroll
    for (int i = 0; i < 8; i++)
        xn[i] = (v[i]-m)*rstd*g[lane*8+i] + b[lane*8+i];
    float logit[8];
#pragma unroll
    for (int e = 0; e < 8; e++) {
        float t = 0.f;
#pragma unroll
        for (int i = 0; i < 8; i++) t += xn[i] * gw[e*DM + lane*8 + i];
#pragma unroll
        for (int o = 1; o < 64; o <<= 1) t += __shfl_xor(t, o);
        logit[e] = t + gb[e];
    }
    if (lane == 0) {
        float mx = -1e30f;
        for (int e = 0; e < 8; e++) mx = fmaxf(mx, logit[e]);
        float den = 0.f, p[8];
        for (int e = 0; e < 8; e++) { p[e] = __expf(logit[e] - mx); den += p[e]; }
        for (int e = 0; e < 8; e++) p[e] /= den;
        int i1 = 0;
        for (int e = 1; e < 8; e++) if (p[e] > p[i1]) i1 = e;
        int i2 = -1;
        for (int e = 0; e < 8; e++) { if (e == i1) continue; if (i2 < 0 || p[e] > p[i2]) i2 = e; }
        int s1 = atomicAdd(&cnt[i1], 1);
        idxl[i1*SQ + s1] = token;  cw[i1*SQ + s1] = p[i1];
        int s2 = atomicAdd(&cnt[i2], 1);
        idxl[i2*SQ + s2] = token;  cw[i2*SQ + s2] = p[i2];
    }
}

// fp32 weight -> split bf16 pair
__global__ __launch_bounds__(256) void cvt_split_w(
    const float* __restrict__ w, u16* __restrict__ wh, u16* __restrict__ wl, int n)
{
    int i = blockIdx.x * 256 + threadIdx.x;
    if (i < n) {
        float v = w[i];
        u16 h = f2bf(v);
        wh[i] = h;
        wl[i] = f2bf(v - bf2f(h));
    }
}

// three fp32 weights -> plain bf16 (n = FF*DM = 2^20 each)
__global__ __launch_bounds__(256) void cvt3_bf16(
    const float* __restrict__ w1, const float* __restrict__ w2,
    const float* __restrict__ w3,
    u16* __restrict__ o1, u16* __restrict__ o2, u16* __restrict__ o3)
{
    int i = blockIdx.x * 256 + threadIdx.x;
    int which = i >> 20;
    int off = i & ((1 << 20) - 1);
    if (which == 0)      o1[off] = f2bf(w1[off]);
    else if (which == 1) o2[off] = f2bf(w2[off]);
    else                 o3[off] = f2bf(w3[off]);
}

__global__ __launch_bounds__(64) void zero_cnt(int* cnt)
{
    if (threadIdx.x < NE) cnt[threadIdx.x] = 0;
}

__global__ __launch_bounds__(256) void init_out(
    const float* __restrict__ x1, float* __restrict__ out)
{
    int i = blockIdx.x * 256 + threadIdx.x;   // float4 index
    ((float4*)out)[i] = ((const float4*)x1)[i];
}

__global__ __launch_bounds__(256) void sentinel_kernel(float* out, float v, int n)
{
    int i = blockIdx.x * 256 + threadIdx.x;
    if (i < n) out[i] = v;
}
__global__ __launch_bounds__(256) void scrub_kernel(float* out, int n)
{
    int i = blockIdx.x * 256 + threadIdx.x;
    if (i < n) { float v = out[i]; if (!isfinite(v)) out[i] = 777.0f; }
}

// ===========================================================================
extern "C" void kernel_launch(void* const* d_in, const int* in_sizes, int n_in,
                              void* d_out, int out_size, void* d_ws, size_t ws_size,
                              hipStream_t stream)
{
    const float* src        = (const float*)d_in[0];
    const float* in_proj_w  = (const float*)d_in[1];
    const float* in_proj_b  = (const float*)d_in[2];
    const float* out_proj_w = (const float*)d_in[3];
    const float* out_proj_b = (const float*)d_in[4];
    const float* ln1_g      = (const float*)d_in[5];
    const float* ln1_b      = (const float*)d_in[6];
    const float* ln2_g      = (const float*)d_in[7];
    const float* ln2_b      = (const float*)d_in[8];
    const float* gate_w     = (const float*)d_in[9];
    const float* gate_b     = (const float*)d_in[10];
    const float* w1         = (const float*)d_in[11];
    const float* b1         = (const float*)d_in[12];
    const float* w2         = (const float*)d_in[13];
    const float* b2         = (const float*)d_in[14];
    const float* wo         = (const float*)d_in[15];
    const float* bo         = (const float*)d_in[16];
    float* out = (float*)d_out;

    const size_t MB = (size_t)1 << 20;
    const size_t ROUTE = 512 * 1024;
    const size_t NEED = ROUTE + 44 * MB;     // peak 44.5 MiB (proven <=48.13)
    if (ws_size < NEED) {
        sentinel_kernel<<<(SQ*DM)/256, 256, 0, stream>>>(out, 333.0f, SQ*DM);
        return;
    }

    char* ws = (char*)d_ws;
    int*   cnt  = (int*)ws;                          // 32 B (+pad)
    int*   idxl = (int*)(ws + 1024);                 // 128 KiB
    float* cw   = (float*)(ws + 1024 + 128*1024);    // 128 KiB
    char*  base = ws + ROUTE;
    // region map (MiB offsets from base), phase-reused:
    u16* xln1h = (u16*)(base);            // [0,4)   A  -> attnh (B)
    u16* xln1l = (u16*)(base + 4*MB);     // [4,8)   A  -> attnl (B)
    u16* attnh = (u16*)(base);
    u16* attnl = (u16*)(base + 4*MB);
    u16* qkvh  = (u16*)(base + 8*MB);     // [8,20)  A,B
    u16* qkvl  = (u16*)(base + 20*MB);    // [20,32) A,B
    u16* a1    = (u16*)(base + 8*MB);     // [8,24)  D (qkv dead)
    u16* w1b   = (u16*)(base + 24*MB);    // [24,26) D
    u16* w2b   = (u16*)(base + 26*MB);    // [26,28) D
    u16* wob   = (u16*)(base + 28*MB);    // [28,30) D
    u16* vth   = (u16*)(base + 32*MB);    // [32,36) A,B
    u16* vtl   = (u16*)(base + 36*MB);    // [36,40) A,B
    float* x1  = (float*)(base + 32*MB);  // [32,40) C+ (vt dead)
    u16* wph   = (u16*)(base + 40*MB);            // [40,41.5) in_proj hi
    u16* wpl   = (u16*)(base + 40*MB + 1536*1024);// [41.5,43) in_proj lo
    u16* woh   = (u16*)(base + 43*MB);            // [43,43.5) out_proj hi
    u16* wol   = (u16*)(base + 43*MB + 512*1024); // [43.5,44) out_proj lo
    u16* xln2  = (u16*)(base + 40*MB);    // [40,44) after outproj (wp/wo dead)

    // ---- weight prep (split pairs for emulated-fp32 gemms) ----
    cvt_split_w<<<(3*DM*DM)/256, 256, 0, stream>>>(in_proj_w,  wph, wpl, 3*DM*DM);
    cvt_split_w<<<(DM*DM)/256,   256, 0, stream>>>(out_proj_w, woh, wol, DM*DM);

    // ---- attention path (emulated fp32) ----
    ln1_split<<<SQ, 256, 0, stream>>>(src, ln1_g, ln1_b, xln1h, xln1l);
    gemm_split<<<dim3(32, 12), 256, 0, stream>>>(
        xln1h, xln1l, DM, wph, wpl, DM, SQ, 3*DM, DM,
        in_proj_b, nullptr, 0, qkvh, qkvl, nullptr, 3*DM, 0);
    transpose_v2<<<(NH*HDIM*SQ)/256, 256, 0, stream>>>(qkvh, qkvl, vth, vtl);
    flash_attn<<<dim3(SQ/64, NH), 256, 0, stream>>>(qkvh, qkvl, vth, vtl, attnh, attnl);
    gemm_split<<<dim3(32, 4), 256, 0, stream>>>(          // x1 = src + attn@Wo^T+b
        attnh, attnl, DM, woh, wol, DM, SQ, DM, DM,
        out_proj_b, src, DM, nullptr, nullptr, x1, DM, 1);

    // ---- MoE (sparse top-2) ----
    ln_kernel<<<SQ, 256, 0, stream>>>(x1, ln2_g, ln2_b, xln2);
    zero_cnt<<<1, 64, 0, stream>>>(cnt);
    gate_route<<<SQ/4, 256, 0, stream>>>(x1, ln2_g, ln2_b, gate_w, gate_b,
                                         cnt, idxl, cw);
    init_out<<<(SQ*DM/4)/256, 256, 0, stream>>>(x1, out);

    for (int e = 0; e < NE; e++) {
        cvt3_bf16<<<(3 << 20) / 256, 256, 0, stream>>>(
            w1 + (size_t)e*FF*DM, w2 + (size_t)e*FF*DM, wo + (size_t)e*DM*FF,
            w1b, w2b, wob);
        gemm_moe12<<<dim3(32, 16), 256, 0, stream>>>(      // h (compact rows)
            xln2, DM, idxl + e*SQ, w1b, w2b, DM, cnt + e, FF, DM,
            b1 + e*FF, b2 + e*FF, a1, FF);
        gemm_moe_y<<<dim3(32, 4), 256, 0, stream>>>(       // out[tok] += cw*(h@wo^T+bo)
            a1, FF, wob, FF, cnt + e, DM, FF,
            bo + e*DM, cw + e*SQ, idxl + e*SQ, out, DM);
    }

    scrub_kernel<<<(SQ*DM)/256, 256, 0, stream>>>(out, SQ*DM);
}

// Round 6
// 843.545 us; speedup vs baseline: 3.8172x; 2.2280x over previous
//
#include <hip/hip_runtime.h>
#include <hip/hip_bf16.h>
#include <math.h>

// S=4096, D=512, H=8, hd=64, F=2048, E=8, top-2. I/O fp32.
// Attention path: split-bf16 (hi+lo, 3-MFMA) emulated fp32 => fp32-faithful
// routing. MoE: sparse top-2, ALL experts in one launch (128-aligned row
// offsets), inline fp32->bf16 B staging, atomic fp32 scatter-add output.
#define SQ   4096
#define DM   512
#define NH   8
#define HDIM 64
#define FF   2048
#define NE   8

typedef unsigned short u16;
typedef unsigned int   u32;
typedef __attribute__((ext_vector_type(8))) __bf16 bf16x8;
typedef __attribute__((ext_vector_type(4))) float  f32x4;

__device__ __forceinline__ float bf2f(u16 v) {
    union { u32 i; float f; } c; c.i = ((u32)v) << 16; return c.f;
}
__device__ __forceinline__ u16 f2bf(float f) {  // RNE
    union { float f; u32 i; } c; c.f = f; u32 u = c.i;
    return (u16)((u + 0x7fffu + ((u >> 16) & 1u)) >> 16);
}

#define BM 128
#define BN 128
#define BK 32
#define BKP 40   // padded LDS row stride (2-way on frag reads -> free)

// ===========================================================================
// Split-bf16 GEMM: C = (Ahi+Alo)@(Bhi+Blo)^T + bias. 3 MFMAs (hh+hl+lh).
// mode 0: split bf16 pair out. mode 1: fp32 out (+resid).
// ===========================================================================
__global__ __launch_bounds__(256) void gemm_split(
    const u16* __restrict__ Ahi, const u16* __restrict__ Alo, int lda,
    const u16* __restrict__ Bhi, const u16* __restrict__ Blo, int ldb,
    int M, int N, int K,
    const float* __restrict__ bias,
    const float* __restrict__ resid, int ldres,
    u16* __restrict__ Chi, u16* __restrict__ Clo,
    float* __restrict__ Cf, int ldc, int mode)
{
    __shared__ __align__(16) u16 Ash[BM * BKP], Asl[BM * BKP];
    __shared__ __align__(16) u16 Bsh[BN * BKP], Bsl[BN * BKP];
    const int tid  = threadIdx.x;
    const int wave = tid >> 6;
    const int lane = tid & 63;
    const int quad = lane >> 4;
    const int l16  = lane & 15;
    const int bm = blockIdx.x * BM;
    const int bn = blockIdx.y * BN;
    const int wm = (wave & 1) * 64;
    const int wn = (wave >> 1) * 64;

    f32x4 acc[4][4];
#pragma unroll
    for (int i = 0; i < 4; i++)
#pragma unroll
        for (int j = 0; j < 4; j++)
#pragma unroll
            for (int r = 0; r < 4; r++) acc[i][j][r] = 0.0f;

    for (int k0 = 0; k0 < K; k0 += BK) {
#pragma unroll
        for (int i = 0; i < 2; i++) {
            int c = tid + i * 256;
            int row = c >> 2;
            int col = (c & 3) << 3;
            int ga = bm + row, gb2 = bn + row;
            uint4 vah = make_uint4(0u,0u,0u,0u), val = vah, vbh = vah, vbl = vah;
            if (ga < M) {
                vah = *(const uint4*)(Ahi + (size_t)ga * lda + k0 + col);
                val = *(const uint4*)(Alo + (size_t)ga * lda + k0 + col);
            }
            if (gb2 < N) {
                vbh = *(const uint4*)(Bhi + (size_t)gb2 * ldb + k0 + col);
                vbl = *(const uint4*)(Blo + (size_t)gb2 * ldb + k0 + col);
            }
            *(uint4*)(Ash + row * BKP + col) = vah;
            *(uint4*)(Asl + row * BKP + col) = val;
            *(uint4*)(Bsh + row * BKP + col) = vbh;
            *(uint4*)(Bsl + row * BKP + col) = vbl;
        }
        __syncthreads();
        bf16x8 ah[4], al[4], bh[4], bl[4];
#pragma unroll
        for (int i = 0; i < 4; i++) {
            ah[i] = *(const bf16x8*)(Ash + (wm + i * 16 + l16) * BKP + quad * 8);
            al[i] = *(const bf16x8*)(Asl + (wm + i * 16 + l16) * BKP + quad * 8);
        }
#pragma unroll
        for (int j = 0; j < 4; j++) {
            bh[j] = *(const bf16x8*)(Bsh + (wn + j * 16 + l16) * BKP + quad * 8);
            bl[j] = *(const bf16x8*)(Bsl + (wn + j * 16 + l16) * BKP + quad * 8);
        }
#pragma unroll
        for (int i = 0; i < 4; i++)
#pragma unroll
            for (int j = 0; j < 4; j++) {
                acc[i][j] = __builtin_amdgcn_mfma_f32_16x16x32_bf16(ah[i], bh[j], acc[i][j], 0,0,0);
                acc[i][j] = __builtin_amdgcn_mfma_f32_16x16x32_bf16(ah[i], bl[j], acc[i][j], 0,0,0);
                acc[i][j] = __builtin_amdgcn_mfma_f32_16x16x32_bf16(al[i], bh[j], acc[i][j], 0,0,0);
            }
        __syncthreads();
    }

#pragma unroll
    for (int i = 0; i < 4; i++)
#pragma unroll
        for (int j = 0; j < 4; j++)
#pragma unroll
            for (int r = 0; r < 4; r++) {
                int row = bm + wm + i * 16 + quad * 4 + r;
                int col = bn + wn + j * 16 + l16;
                if (row >= M || col >= N) continue;
                float v = acc[i][j][r] + (bias ? bias[col] : 0.0f);
                size_t idx = (size_t)row * ldc + col;
                if (mode == 0) {
                    u16 hb = f2bf(v);
                    Chi[idx] = hb;
                    Clo[idx] = f2bf(v - bf2f(hb));
                } else {
                    if (resid) v += resid[(size_t)row * ldres + col];
                    Cf[idx] = v;
                }
            }
}

// ===========================================================================
// MoE all-expert fused w1/w2 GEMM: h = silu(x@w1^T+b1)*(x@w2^T+b2)
// grid (72, 16). Block finds its expert via 128-aligned offset table.
// A rows gathered via idxl; B staged fp32->bf16 inline.
// ===========================================================================
__global__ __launch_bounds__(256) void moe12_all(
    const u16* __restrict__ A, int lda,
    const int* __restrict__ idxl, const int* __restrict__ cnt,
    const int* __restrict__ off,
    const float* __restrict__ w1, const float* __restrict__ b1,
    const float* __restrict__ w2, const float* __restrict__ b2,
    u16* __restrict__ H)
{
    const int bmg = blockIdx.x * BM;
    if (bmg >= off[NE]) return;
    int e = 0;
    while (e < NE - 1 && bmg >= off[e + 1]) e++;
    const int M   = cnt[e];
    const int bml = bmg - off[e];
    if (bml >= M) return;
    const float* B1 = w1 + (size_t)e * FF * DM;
    const float* B2 = w2 + (size_t)e * FF * DM;
    const int*   rl = idxl + e * SQ;

    __shared__ __align__(16) u16 As[BM * BKP], Bs1[BN * BKP], Bs2[BN * BKP];
    const int tid  = threadIdx.x;
    const int wave = tid >> 6;
    const int lane = tid & 63;
    const int quad = lane >> 4;
    const int l16  = lane & 15;
    const int bn = blockIdx.y * BN;
    const int wm = (wave & 1) * 64;
    const int wn = (wave >> 1) * 64;

    f32x4 acc1[4][4], acc2[4][4];
#pragma unroll
    for (int i = 0; i < 4; i++)
#pragma unroll
        for (int j = 0; j < 4; j++)
#pragma unroll
            for (int r = 0; r < 4; r++) { acc1[i][j][r] = 0.0f; acc2[i][j][r] = 0.0f; }

    for (int k0 = 0; k0 < DM; k0 += BK) {
#pragma unroll
        for (int i = 0; i < 2; i++) {
            int c = tid + i * 256;
            int row = c >> 2;
            int col = (c & 3) << 3;
            uint4 va = make_uint4(0u,0u,0u,0u);
            int lr = bml + row;
            if (lr < M) {
                int ar = rl[lr];
                va = *(const uint4*)(A + (size_t)ar * lda + k0 + col);
            }
            *(uint4*)(As + row * BKP + col) = va;
        }
#pragma unroll
        for (int i = 0; i < 4; i++) {
            int c = tid + i * 256;
            int row = c >> 3;
            int col = (c & 7) << 2;
            float4 v1 = *(const float4*)(B1 + (size_t)(bn + row) * DM + k0 + col);
            float4 v2 = *(const float4*)(B2 + (size_t)(bn + row) * DM + k0 + col);
            ushort4 h1, h2;
            h1.x = f2bf(v1.x); h1.y = f2bf(v1.y); h1.z = f2bf(v1.z); h1.w = f2bf(v1.w);
            h2.x = f2bf(v2.x); h2.y = f2bf(v2.y); h2.z = f2bf(v2.z); h2.w = f2bf(v2.w);
            *(ushort4*)(Bs1 + row * BKP + col) = h1;
            *(ushort4*)(Bs2 + row * BKP + col) = h2;
        }
        __syncthreads();
        bf16x8 af[4], b1f[4], b2f[4];
#pragma unroll
        for (int i = 0; i < 4; i++)
            af[i] = *(const bf16x8*)(As + (wm + i * 16 + l16) * BKP + quad * 8);
#pragma unroll
        for (int j = 0; j < 4; j++) {
            b1f[j] = *(const bf16x8*)(Bs1 + (wn + j * 16 + l16) * BKP + quad * 8);
            b2f[j] = *(const bf16x8*)(Bs2 + (wn + j * 16 + l16) * BKP + quad * 8);
        }
#pragma unroll
        for (int i = 0; i < 4; i++)
#pragma unroll
            for (int j = 0; j < 4; j++) {
                acc1[i][j] = __builtin_amdgcn_mfma_f32_16x16x32_bf16(af[i], b1f[j], acc1[i][j], 0,0,0);
                acc2[i][j] = __builtin_amdgcn_mfma_f32_16x16x32_bf16(af[i], b2f[j], acc2[i][j], 0,0,0);
            }
        __syncthreads();
    }

#pragma unroll
    for (int i = 0; i < 4; i++)
#pragma unroll
        for (int j = 0; j < 4; j++)
#pragma unroll
            for (int r = 0; r < 4; r++) {
                int rowl = bml + wm + i * 16 + quad * 4 + r;
                if (rowl >= M) continue;
                int col = bn + wn + j * 16 + l16;
                float g1 = acc1[i][j][r] + b1[e * FF + col];
                float g2 = acc2[i][j][r] + b2[e * FF + col];
                float s  = g1 / (1.0f + __expf(-g1));
                H[(size_t)(off[e] + rowl) * FF + col] = f2bf(s * g2);
            }
}

// ===========================================================================
// MoE all-expert down-proj: out[tok] += cw*(h@wo^T + bo). grid (72, 4).
// Concurrent experts -> atomicAdd (a token appears in exactly 2 lists).
// ===========================================================================
__global__ __launch_bounds__(256) void moe_y_all(
    const u16* __restrict__ H,
    const float* __restrict__ wo, const float* __restrict__ bo,
    const int* __restrict__ idxl, const float* __restrict__ cw,
    const int* __restrict__ cnt, const int* __restrict__ off,
    float* __restrict__ out)
{
    const int bmg = blockIdx.x * BM;
    if (bmg >= off[NE]) return;
    int e = 0;
    while (e < NE - 1 && bmg >= off[e + 1]) e++;
    const int M   = cnt[e];
    const int bml = bmg - off[e];
    if (bml >= M) return;
    const float* B = wo + (size_t)e * DM * FF;

    __shared__ __align__(16) u16 As[BM * BKP], Bs[BN * BKP];
    const int tid  = threadIdx.x;
    const int wave = tid >> 6;
    const int lane = tid & 63;
    const int quad = lane >> 4;
    const int l16  = lane & 15;
    const int bn = blockIdx.y * BN;
    const int wm = (wave & 1) * 64;
    const int wn = (wave >> 1) * 64;

    f32x4 acc[4][4];
#pragma unroll
    for (int i = 0; i < 4; i++)
#pragma unroll
        for (int j = 0; j < 4; j++)
#pragma unroll
            for (int r = 0; r < 4; r++) acc[i][j][r] = 0.0f;

    for (int k0 = 0; k0 < FF; k0 += BK) {
#pragma unroll
        for (int i = 0; i < 2; i++) {
            int c = tid + i * 256;
            int row = c >> 2;
            int col = (c & 3) << 3;
            uint4 va = *(const uint4*)(H + (size_t)(bmg + row) * FF + k0 + col);
            *(uint4*)(As + row * BKP + col) = va;
        }
#pragma unroll
        for (int i = 0; i < 4; i++) {
            int c = tid + i * 256;
            int row = c >> 3;
            int col = (c & 7) << 2;
            float4 v = *(const float4*)(B + (size_t)(bn + row) * FF + k0 + col);
            ushort4 h;
            h.x = f2bf(v.x); h.y = f2bf(v.y); h.z = f2bf(v.z); h.w = f2bf(v.w);
            *(ushort4*)(Bs + row * BKP + col) = h;
        }
        __syncthreads();
        bf16x8 af[4], bf[4];
#pragma unroll
        for (int i = 0; i < 4; i++)
            af[i] = *(const bf16x8*)(As + (wm + i * 16 + l16) * BKP + quad * 8);
#pragma unroll
        for (int j = 0; j < 4; j++)
            bf[j] = *(const bf16x8*)(Bs + (wn + j * 16 + l16) * BKP + quad * 8);
#pragma unroll
        for (int i = 0; i < 4; i++)
#pragma unroll
            for (int j = 0; j < 4; j++)
                acc[i][j] = __builtin_amdgcn_mfma_f32_16x16x32_bf16(af[i], bf[j], acc[i][j], 0,0,0);
        __syncthreads();
    }

#pragma unroll
    for (int i = 0; i < 4; i++)
#pragma unroll
        for (int j = 0; j < 4; j++)
#pragma unroll
            for (int r = 0; r < 4; r++) {
                int rowl = bml + wm + i * 16 + quad * 4 + r;
                if (rowl >= M) continue;
                int col = bn + wn + j * 16 + l16;
                int tok = idxl[e * SQ + rowl];
                float wgt = cw[e * SQ + rowl];
                atomicAdd(out + (size_t)tok * DM + col,
                          wgt * (acc[i][j][r] + bo[e * DM + col]));
            }
}

// ===========================================================================
// Flash attention, split precision. 64-row Q tiles, grid (64, 8), 256 thr.
// exp2-domain softmax; wave-private P buffer (no mid-tile barrier: per-wave
// DS ops are in-order, compiler keeps aliasing store->load order).
// ===========================================================================
#define KP 72
#define SCL 0.18033688011112042f   // 0.125 * log2(e)
__global__ __launch_bounds__(256) void flash_attn(
    const u16* __restrict__ qh, const u16* __restrict__ ql,   // [4096,1536]
    const u16* __restrict__ vth, const u16* __restrict__ vtl, // [512,4096]
    u16* __restrict__ oh, u16* __restrict__ ol)               // [4096,512]
{
    __shared__ __align__(16) u16 Ksh[64*KP], Ksl[64*KP], Vsh[64*KP], Vsl[64*KP];
    __shared__ __align__(16) u16 Psh[4][16*KP], Psl[4][16*KP];
    const int tid  = threadIdx.x;
    const int wave = tid >> 6;
    const int lane = tid & 63;
    const int quad = lane >> 4;
    const int l16  = lane & 15;
    const int h    = blockIdx.y;
    const int qbase = blockIdx.x * 64 + wave * 16;

    bf16x8 aqh[2], aql[2];
#pragma unroll
    for (int kk = 0; kk < 2; kk++) {
        size_t off = (size_t)(qbase + l16) * (3*DM) + h*HDIM + kk*32 + quad*8;
        aqh[kk] = *(const bf16x8*)(qh + off);
        aql[kk] = *(const bf16x8*)(ql + off);
    }

    float m_[4], l_[4];
    f32x4 o_[4];
#pragma unroll
    for (int r = 0; r < 4; r++) { m_[r] = -1e30f; l_[r] = 0.0f; }
#pragma unroll
    for (int nd = 0; nd < 4; nd++)
#pragma unroll
        for (int r = 0; r < 4; r++) o_[nd][r] = 0.0f;

    for (int jt = 0; jt < SQ / 64; jt++) {
#pragma unroll
        for (int i = 0; i < 2; i++) {
            int c = tid + i * 256;
            int r = c >> 3;
            int co = (c & 7) << 3;
            size_t koff = (size_t)(jt*64 + r) * (3*DM) + DM + h*HDIM + co;
            size_t voff = (size_t)(h*HDIM + r) * SQ + jt*64 + co;
            *(uint4*)(Ksh + r*KP + co) = *(const uint4*)(qh + koff);
            *(uint4*)(Ksl + r*KP + co) = *(const uint4*)(ql + koff);
            *(uint4*)(Vsh + r*KP + co) = *(const uint4*)(vth + voff);
            *(uint4*)(Vsl + r*KP + co) = *(const uint4*)(vtl + voff);
        }
        __syncthreads();

        f32x4 s[4];
#pragma unroll
        for (int jn = 0; jn < 4; jn++) {
            f32x4 z;
#pragma unroll
            for (int r = 0; r < 4; r++) z[r] = 0.0f;
#pragma unroll
            for (int kk = 0; kk < 2; kk++) {
                bf16x8 kh = *(const bf16x8*)(Ksh + (jn*16 + l16)*KP + kk*32 + quad*8);
                bf16x8 kl = *(const bf16x8*)(Ksl + (jn*16 + l16)*KP + kk*32 + quad*8);
                z = __builtin_amdgcn_mfma_f32_16x16x32_bf16(aqh[kk], kh, z, 0,0,0);
                z = __builtin_amdgcn_mfma_f32_16x16x32_bf16(aqh[kk], kl, z, 0,0,0);
                z = __builtin_amdgcn_mfma_f32_16x16x32_bf16(aql[kk], kh, z, 0,0,0);
            }
#pragma unroll
            for (int r = 0; r < 4; r++) z[r] *= SCL;   // exp2 domain
            s[jn] = z;
        }

        float mx[4], al2[4], rs[4];
#pragma unroll
        for (int r = 0; r < 4; r++)
            mx[r] = fmaxf(fmaxf(s[0][r], s[1][r]), fmaxf(s[2][r], s[3][r]));
#pragma unroll
        for (int r = 0; r < 4; r++) {
#pragma unroll
            for (int o2 = 1; o2 < 16; o2 <<= 1)
                mx[r] = fmaxf(mx[r], __shfl_xor(mx[r], o2));
            float nm = fmaxf(m_[r], mx[r]);
            al2[r] = exp2f(m_[r] - nm);
            m_[r] = nm;
            rs[r] = 0.0f;
        }
#pragma unroll
        for (int jn = 0; jn < 4; jn++)
#pragma unroll
            for (int r = 0; r < 4; r++) {
                float p = exp2f(s[jn][r] - m_[r]);
                s[jn][r] = p;
                rs[r] += p;
            }
#pragma unroll
        for (int r = 0; r < 4; r++) {
#pragma unroll
            for (int o2 = 1; o2 < 16; o2 <<= 1)
                rs[r] += __shfl_xor(rs[r], o2);
            l_[r] = l_[r] * al2[r] + rs[r];
        }
#pragma unroll
        for (int nd = 0; nd < 4; nd++)
#pragma unroll
            for (int r = 0; r < 4; r++) o_[nd][r] *= al2[r];
#pragma unroll
        for (int jn = 0; jn < 4; jn++)
#pragma unroll
            for (int r = 0; r < 4; r++) {
                float p = s[jn][r];
                u16 ph = f2bf(p);
                int pidx = (quad*4 + r)*KP + jn*16 + l16;
                Psh[wave][pidx] = ph;
                Psl[wave][pidx] = f2bf(p - bf2f(ph));
            }
        // no barrier: Ps is wave-private; per-wave DS ops execute in order

        bf16x8 ph[2], pl[2];
#pragma unroll
        for (int kk = 0; kk < 2; kk++) {
            ph[kk] = *(const bf16x8*)(Psh[wave] + l16*KP + kk*32 + quad*8);
            pl[kk] = *(const bf16x8*)(Psl[wave] + l16*KP + kk*32 + quad*8);
        }
#pragma unroll
        for (int nd = 0; nd < 4; nd++) {
#pragma unroll
            for (int kk = 0; kk < 2; kk++) {
                bf16x8 vh = *(const bf16x8*)(Vsh + (nd*16 + l16)*KP + kk*32 + quad*8);
                bf16x8 vl = *(const bf16x8*)(Vsl + (nd*16 + l16)*KP + kk*32 + quad*8);
                o_[nd] = __builtin_amdgcn_mfma_f32_16x16x32_bf16(ph[kk], vh, o_[nd], 0,0,0);
                o_[nd] = __builtin_amdgcn_mfma_f32_16x16x32_bf16(ph[kk], vl, o_[nd], 0,0,0);
                o_[nd] = __builtin_amdgcn_mfma_f32_16x16x32_bf16(pl[kk], vh, o_[nd], 0,0,0);
            }
        }
        __syncthreads();   // before next tile overwrites Ks/Vs
    }

#pragma unroll
    for (int nd = 0; nd < 4; nd++)
#pragma unroll
        for (int r = 0; r < 4; r++) {
            int row = qbase + quad*4 + r;
            int col = h*HDIM + nd*16 + l16;
            float w = o_[nd][r] / l_[r];
            u16 hb = f2bf(w);
            oh[(size_t)row * DM + col] = hb;
            ol[(size_t)row * DM + col] = f2bf(w - bf2f(hb));
        }
}

// LN1: fp32 in -> split bf16 pair out.
__global__ __launch_bounds__(256) void ln1_split(
    const float* __restrict__ x, const float* __restrict__ g,
    const float* __restrict__ b, u16* __restrict__ ohi, u16* __restrict__ olo)
{
    const int row = blockIdx.x;
    const int tid = threadIdx.x;
    float v0 = x[(size_t)row * DM + tid];
    float v1 = x[(size_t)row * DM + tid + 256];
    float s = v0 + v1, sq = v0*v0 + v1*v1;
#pragma unroll
    for (int o = 1; o < 64; o <<= 1) { s += __shfl_xor(s, o); sq += __shfl_xor(sq, o); }
    __shared__ float ss[4], ssq[4];
    if ((tid & 63) == 0) { ss[tid>>6] = s; ssq[tid>>6] = sq; }
    __syncthreads();
    s  = ss[0]+ss[1]+ss[2]+ss[3];
    sq = ssq[0]+ssq[1]+ssq[2]+ssq[3];
    float m = s * (1.0f/DM);
    float rstd = rsqrtf(sq*(1.0f/DM) - m*m + 1e-5f);
    float y0 = (v0-m)*rstd*g[tid]     + b[tid];
    float y1 = (v1-m)*rstd*g[tid+256] + b[tid+256];
    u16 h0 = f2bf(y0), h1 = f2bf(y1);
    ohi[(size_t)row*DM + tid]       = h0;  olo[(size_t)row*DM + tid]       = f2bf(y0 - bf2f(h0));
    ohi[(size_t)row*DM + tid + 256] = h1;  olo[(size_t)row*DM + tid + 256] = f2bf(y1 - bf2f(h1));
}

// LN2: fp32 in -> plain bf16 out
__global__ __launch_bounds__(256) void ln_kernel(
    const float* __restrict__ x, const float* __restrict__ g,
    const float* __restrict__ b, u16* __restrict__ out)
{
    const int row = blockIdx.x;
    const int tid = threadIdx.x;
    float v0 = x[(size_t)row * DM + tid];
    float v1 = x[(size_t)row * DM + tid + 256];
    float s = v0 + v1, sq = v0*v0 + v1*v1;
#pragma unroll
    for (int o = 1; o < 64; o <<= 1) { s += __shfl_xor(s, o); sq += __shfl_xor(sq, o); }
    __shared__ float ss[4], ssq[4];
    if ((tid & 63) == 0) { ss[tid>>6] = s; ssq[tid>>6] = sq; }
    __syncthreads();
    s  = ss[0]+ss[1]+ss[2]+ss[3];
    sq = ssq[0]+ssq[1]+ssq[2]+ssq[3];
    float m = s * (1.0f/DM);
    float rstd = rsqrtf(sq*(1.0f/DM) - m*m + 1e-5f);
    out[(size_t)row*DM + tid]       = f2bf((v0-m)*rstd*g[tid]     + b[tid]);
    out[(size_t)row*DM + tid + 256] = f2bf((v1-m)*rstd*g[tid+256] + b[tid+256]);
}

// Coalesced V transpose via LDS 64x64 tiles (pad 66: both phases conflict-free)
__global__ __launch_bounds__(256) void transpose_v2(
    const u16* __restrict__ qh, const u16* __restrict__ ql,
    u16* __restrict__ vth, u16* __restrict__ vtl)
{
    __shared__ u16 Th[64 * 66], Tl[64 * 66];
    const int t0  = blockIdx.x * 64;
    const int hd0 = blockIdx.y * 64;
    const int tid = threadIdx.x;
#pragma unroll
    for (int k = 0; k < 16; k++) {
        int idx = tid + k * 256;
        int r = idx >> 6, j = idx & 63;      // r: token, j: dim (coalesced)
        size_t src = (size_t)(t0 + r) * (3*DM) + 2*DM + hd0 + j;
        Th[r * 66 + j] = qh[src];
        Tl[r * 66 + j] = ql[src];
    }
    __syncthreads();
#pragma unroll
    for (int k = 0; k < 16; k++) {
        int idx = tid + k * 256;
        int r = idx >> 6, c2 = idx & 63;     // r: dim, c2: token (coalesced)
        size_t dst = (size_t)(hd0 + r) * SQ + t0 + c2;
        vth[dst] = Th[c2 * 66 + r];
        vtl[dst] = Tl[c2 * 66 + r];
    }
}

// Gate (own fp32 LN2) + top-2 compaction into per-expert lists.
__global__ __launch_bounds__(256) void gate_route(
    const float* __restrict__ x1, const float* __restrict__ g,
    const float* __restrict__ b, const float* __restrict__ gw,
    const float* __restrict__ gb,
    int* __restrict__ cnt, int* __restrict__ idxl, float* __restrict__ cw)
{
    const int token = blockIdx.x * 4 + (threadIdx.x >> 6);
    const int lane  = threadIdx.x & 63;
    const float* xr = x1 + (size_t)token * DM;
    float v[8];
#pragma unroll
    for (int i = 0; i < 8; i++) v[i] = xr[lane*8 + i];
    float s = 0.f, sq = 0.f;
#pragma unroll
    for (int i = 0; i < 8; i++) { s += v[i]; sq += v[i]*v[i]; }
#pragma unroll
    for (int o = 1; o < 64; o <<= 1) { s += __shfl_xor(s, o); sq += __shfl_xor(sq, o); }
    float m = s * (1.0f/DM);
    float rstd = rsqrtf(sq*(1.0f/DM) - m*m + 1e-5f);
    float xn[8];
#pragma unroll
    for (int i = 0; i < 8; i++)
        xn[i] = (v[i]-m)*rstd*g[lane*8+i] + b[lane*8+i];
    float logit[8];
#pragma unroll
    for (int e = 0; e < 8; e++) {
        float t = 0.f;
#pragma unroll
        for (int i = 0; i < 8; i++) t += xn[i] * gw[e*DM + lane*8 + i];
#pragma unroll
        for (int o = 1; o < 64; o <<= 1) t += __shfl_xor(t, o);
        logit[e] = t + gb[e];
    }
    if (lane == 0) {
        float mx = -1e30f;
        for (int e = 0; e < 8; e++) mx = fmaxf(mx, logit[e]);
        float den = 0.f, p[8];
        for (int e = 0; e < 8; e++) { p[e] = __expf(logit[e] - mx); den += p[e]; }
        for (int e = 0; e < 8; e++) p[e] /= den;
        int i1 = 0;
        for (int e = 1; e < 8; e++) if (p[e] > p[i1]) i1 = e;
        int i2 = -1;
        for (int e = 0; e < 8; e++) { if (e == i1) continue; if (i2 < 0 || p[e] > p[i2]) i2 = e; }
        int s1 = atomicAdd(&cnt[i1], 1);
        idxl[i1*SQ + s1] = token;  cw[i1*SQ + s1] = p[i1];
        int s2 = atomicAdd(&cnt[i2], 1);
        idxl[i2*SQ + s2] = token;  cw[i2*SQ + s2] = p[i2];
    }
}

// fp32 weight -> split bf16 pair
__global__ __launch_bounds__(256) void cvt_split_w(
    const float* __restrict__ w, u16* __restrict__ wh, u16* __restrict__ wl, int n)
{
    int i = blockIdx.x * 256 + threadIdx.x;
    if (i < n) {
        float v = w[i];
        u16 h = f2bf(v);
        wh[i] = h;
        wl[i] = f2bf(v - bf2f(h));
    }
}

__global__ __launch_bounds__(64) void zero_cnt(int* cnt)
{
    if (threadIdx.x < NE) cnt[threadIdx.x] = 0;
}

// 128-aligned exclusive cumsum of cnt -> off[0..NE]
__global__ __launch_bounds__(64) void make_off(const int* __restrict__ cnt,
                                              int* __restrict__ off)
{
    if (threadIdx.x == 0) {
        int a = 0;
        for (int e = 0; e < NE; e++) {
            off[e] = a;
            a += ((cnt[e] + 127) >> 7) << 7;
        }
        off[NE] = a;
    }
}

__global__ __launch_bounds__(256) void init_out(
    const float* __restrict__ x1, float* __restrict__ out)
{
    int i = blockIdx.x * 256 + threadIdx.x;   // float4 index
    ((float4*)out)[i] = ((const float4*)x1)[i];
}

__global__ __launch_bounds__(256) void sentinel_kernel(float* out, float v, int n)
{
    int i = blockIdx.x * 256 + threadIdx.x;
    if (i < n) out[i] = v;
}
__global__ __launch_bounds__(256) void scrub_kernel(float* out, int n)
{
    int i = blockIdx.x * 256 + threadIdx.x;
    if (i < n) { float v = out[i]; if (!isfinite(v)) out[i] = 777.0f; }
}

// ===========================================================================
extern "C" void kernel_launch(void* const* d_in, const int* in_sizes, int n_in,
                              void* d_out, int out_size, void* d_ws, size_t ws_size,
                              hipStream_t stream)
{
    const float* src        = (const float*)d_in[0];
    const float* in_proj_w  = (const float*)d_in[1];
    const float* in_proj_b  = (const float*)d_in[2];
    const float* out_proj_w = (const float*)d_in[3];
    const float* out_proj_b = (const float*)d_in[4];
    const float* ln1_g      = (const float*)d_in[5];
    const float* ln1_b      = (const float*)d_in[6];
    const float* ln2_g      = (const float*)d_in[7];
    const float* ln2_b      = (const float*)d_in[8];
    const float* gate_w     = (const float*)d_in[9];
    const float* gate_b     = (const float*)d_in[10];
    const float* w1         = (const float*)d_in[11];
    const float* b1         = (const float*)d_in[12];
    const float* w2         = (const float*)d_in[13];
    const float* b2         = (const float*)d_in[14];
    const float* wo         = (const float*)d_in[15];
    const float* bo         = (const float*)d_in[16];
    float* out = (float*)d_out;

    const size_t MB = (size_t)1 << 20;
    const size_t ROUTE = 512 * 1024;
    const size_t NEED = ROUTE + 44 * MB;     // peak 44.5 MiB (proven fits)
    if (ws_size < NEED) {
        sentinel_kernel<<<(SQ*DM)/256, 256, 0, stream>>>(out, 333.0f, SQ*DM);
        return;
    }

    char* ws = (char*)d_ws;
    int*   cnt  = (int*)ws;                          // 8 ints
    int*   offp = (int*)(ws + 64);                   // 9 ints
    int*   idxl = (int*)(ws + 1024);                 // 128 KiB
    float* cw   = (float*)(ws + 1024 + 128*1024);    // 128 KiB
    char*  base = ws + ROUTE;
    // phase-reused regions (MiB offsets from base):
    u16* xln1h = (u16*)(base);            // [0,4)   A  -> attnh (B)
    u16* xln1l = (u16*)(base + 4*MB);     // [4,8)   A  -> attnl (B)
    u16* attnh = (u16*)(base);
    u16* attnl = (u16*)(base + 4*MB);
    u16* qkvh  = (u16*)(base + 8*MB);     // [8,20)  A,B
    u16* qkvl  = (u16*)(base + 20*MB);    // [20,32) A,B
    float* x1  = (float*)(base + 8*MB);   // [8,16)  C (qkv dead after flash)
    u16* vth   = (u16*)(base + 32*MB);    // [32,36) A,B
    u16* vtl   = (u16*)(base + 36*MB);    // [36,40) A,B
    u16* xln2  = (u16*)(base + 36*MB);    // [36,40) C (vtl dead)
    u16* Hbuf  = (u16*)(base);            // [0,36)  D (9216 x 2048 bf16)
    u16* wph   = (u16*)(base + 40*MB);            // [40,41.5) in_proj hi
    u16* wpl   = (u16*)(base + 40*MB + 1536*1024);// [41.5,43) in_proj lo
    u16* woh   = (u16*)(base + 43*MB);            // [43,43.5) out_proj hi
    u16* wol   = (u16*)(base + 43*MB + 512*1024); // [43.5,44) out_proj lo

    // ---- weight prep ----
    cvt_split_w<<<(3*DM*DM)/256, 256, 0, stream>>>(in_proj_w,  wph, wpl, 3*DM*DM);
    cvt_split_w<<<(DM*DM)/256,   256, 0, stream>>>(out_proj_w, woh, wol, DM*DM);

    // ---- attention path (emulated fp32) ----
    ln1_split<<<SQ, 256, 0, stream>>>(src, ln1_g, ln1_b, xln1h, xln1l);
    gemm_split<<<dim3(32, 12), 256, 0, stream>>>(
        xln1h, xln1l, DM, wph, wpl, DM, SQ, 3*DM, DM,
        in_proj_b, nullptr, 0, qkvh, qkvl, nullptr, 3*DM, 0);
    transpose_v2<<<dim3(SQ/64, DM/64), 256, 0, stream>>>(qkvh, qkvl, vth, vtl);
    flash_attn<<<dim3(SQ/64, NH), 256, 0, stream>>>(qkvh, qkvl, vth, vtl, attnh, attnl);
    gemm_split<<<dim3(32, 4), 256, 0, stream>>>(          // x1 = src + attn@Wo^T+b
        attnh, attnl, DM, woh, wol, DM, SQ, DM, DM,
        out_proj_b, src, DM, nullptr, nullptr, x1, DM, 1);

    // ---- MoE (sparse top-2, all experts concurrent) ----
    ln_kernel<<<SQ, 256, 0, stream>>>(x1, ln2_g, ln2_b, xln2);
    zero_cnt<<<1, 64, 0, stream>>>(cnt);
    gate_route<<<SQ/4, 256, 0, stream>>>(x1, ln2_g, ln2_b, gate_w, gate_b,
                                         cnt, idxl, cw);
    make_off<<<1, 64, 0, stream>>>(cnt, offp);
    init_out<<<(SQ*DM/4)/256, 256, 0, stream>>>(x1, out);   // last read of x1
    moe12_all<<<dim3(72, 16), 256, 0, stream>>>(            // H (overwrites [0,36M))
        xln2, DM, idxl, cnt, offp, w1, b1, w2, b2, Hbuf);
    moe_y_all<<<dim3(72, 4), 256, 0, stream>>>(
        Hbuf, wo, bo, idxl, cw, cnt, offp, out);

    scrub_kernel<<<(SQ*DM)/256, 256, 0, stream>>>(out, SQ*DM);
}